// Round 1
// baseline (113.910 us; speedup 1.0000x reference)
//
#include <hip/hip_runtime.h>

// HadamardProj: the reference's fwht butterflies pair bit-0 every step with no
// stride change, so 2 steps = 2*I; 10 steps = 32*I; the d^-0.5 = 1/32 scaling
// cancels it. fwht == identity, hence:
//   out[b,s,d] = x[b,s,d] * scales[0][d]*scales[1][d]*...*scales[4][d]
// Pure streaming elementwise multiply: 64 MiB in + 64 MiB out => ~21 us floor.

#define D_DIM 1024
#define D4 (D_DIM / 4)   // 256 float4 per row

__global__ __launch_bounds__(256) void hadamard_proj_kernel(
    const float4* __restrict__ x,
    const float*  __restrict__ scales,
    float4*       __restrict__ out,
    int n4, int n_scales)
{
    const int tid    = blockIdx.x * blockDim.x + threadIdx.x;
    const int stride = gridDim.x * blockDim.x;   // 524288: multiple of D4, so
                                                 // d4 is invariant per thread
    const int d4 = tid & (D4 - 1);

    // Combined scale for this thread's fixed column group (registers, once).
    const float4* s4 = (const float4*)scales;
    float4 cs = s4[d4];
    #pragma unroll
    for (int i = 1; i < 5; ++i) {
        if (i < n_scales) {
            float4 s = s4[i * D4 + d4];
            cs.x *= s.x; cs.y *= s.y; cs.z *= s.z; cs.w *= s.w;
        }
    }

    for (int i = tid; i < n4; i += stride) {
        float4 xv = x[i];
        float4 o;
        o.x = xv.x * cs.x;
        o.y = xv.y * cs.y;
        o.z = xv.z * cs.z;
        o.w = xv.w * cs.w;
        out[i] = o;
    }
}

extern "C" void kernel_launch(void* const* d_in, const int* in_sizes, int n_in,
                              void* d_out, int out_size, void* d_ws, size_t ws_size,
                              hipStream_t stream) {
    const float* x      = (const float*)d_in[0];
    const float* scales = (const float*)d_in[1];
    float*       out    = (float*)d_out;

    const int n4       = out_size / 4;            // 4,194,304 float4s
    const int n_scales = in_sizes[1] / D_DIM;     // 5

    const int block = 256;
    const int grid  = 2048;  // 8 blocks/CU on 256 CUs; 8 iterations/thread

    hadamard_proj_kernel<<<grid, block, 0, stream>>>(
        (const float4*)x, scales, (float4*)out, n4, n_scales);
}